// Round 1
// baseline (217.377 us; speedup 1.0000x reference)
//
#include <hip/hip_runtime.h>

// CRF forward (log partition) on MI355X.
// B=2048 batches, S=512 steps, T=32 tags. One wave per batch:
// 64 lanes = 32 tags x 2 j-halves. Log2-domain throughout.

constexpr int SEQ = 512;
constexpr int NTAGS = 32;
constexpr int START_TAG = 30;
constexpr int STOP_TAG = 31;
constexpr float LOG2E = 1.4426950408889634f;
constexpr float LN2 = 0.6931471805599453f;

#if __has_builtin(__builtin_amdgcn_exp2f)
#define EXP2(x) __builtin_amdgcn_exp2f(x)
#else
#define EXP2(x) exp2f(x)
#endif
#if __has_builtin(__builtin_amdgcn_logf)
#define LOG2(x) __builtin_amdgcn_logf(x)
#else
#define LOG2(x) log2f(x)
#endif

__global__ __launch_bounds__(64, 8) void crf_fwd_kernel(
    const float* __restrict__ feat, const float* __restrict__ trans,
    float* __restrict__ out) {
  const int tid = threadIdx.x;  // 0..63
  const int h = tid >> 5;       // j-half: 0 -> j in [0,16), 1 -> j in [16,32)
  const int i = tid & 31;       // output tag (replicated across halves)
  const int b = blockIdx.x;     // batch

  // union so float-scalar writes and float4 reads legally alias
  __shared__ union {
    float f[NTAGS];
    float4 v[NTAGS / 4];
  } pb;

  // E[k] = exp(trans[i][16h+k]) = 2^(trans*log2e). NEG_INF rows/cols -> 0.
  float E[16];
#pragma unroll
  for (int k = 0; k < 16; ++k)
    E[k] = EXP2(trans[i * 32 + h * 16 + k] * LOG2E);
  const float tstop = trans[STOP_TAG * 32 + i] * LOG2E;

  // stored log2-alpha relative to running shift zacc; r = pending (stale) shift
  float s = (i == START_TAG) ? 0.0f : -14427.0f;  // -10000*log2e
  float zacc = 0.0f;
  float r = 0.0f;

  const float* Fp = feat + (size_t)b * (SEQ * NTAGS) + i;
  float em[16];
#pragma unroll
  for (int u = 0; u < 16; ++u) em[u] = Fp[u * 32];
  Fp += 16 * 32;

  auto step = [&](float emv) {
    float p = EXP2(s);  // bounded: s <= ~+40 after renorm
    pb.f[i] = p;        // both halves write the same value (one wins)
    // read my half's 16 p values (broadcast reads, wave-order guarantees RAW)
    float4 q0 = pb.v[h * 4 + 0];
    float4 q1 = pb.v[h * 4 + 1];
    float4 q2 = pb.v[h * 4 + 2];
    float4 q3 = pb.v[h * 4 + 3];
    // half-dot: 16 FMAs in 4 parallel chains
    float a0 = E[0] * q0.x;
    a0 = fmaf(E[1], q0.y, a0); a0 = fmaf(E[2], q0.z, a0); a0 = fmaf(E[3], q0.w, a0);
    float a1 = E[4] * q1.x;
    a1 = fmaf(E[5], q1.y, a1); a1 = fmaf(E[6], q1.z, a1); a1 = fmaf(E[7], q1.w, a1);
    float a2 = E[8] * q2.x;
    a2 = fmaf(E[9], q2.y, a2); a2 = fmaf(E[10], q2.z, a2); a2 = fmaf(E[11], q2.w, a2);
    float a3 = E[12] * q3.x;
    a3 = fmaf(E[13], q3.y, a3); a3 = fmaf(E[14], q3.z, a3); a3 = fmaf(E[15], q3.w, a3);
    float acc = (a0 + a1) + (a2 + a3);
    // combine the two j-halves
    acc += __shfl_xor(acc, 32, 64);
    float anew = LOG2(acc);
    anew = fmaf(emv, LOG2E, anew);
    // apply the pending (one-step-stale) renorm shift; keeps |s| bounded
    anew -= r;
    zacc += r;
    s = anew;
    r = __int_as_float(__builtin_amdgcn_readfirstlane(__float_as_int(anew)));
  };

  // 31 blocks of 16 steps with 16-deep emission prefetch, then epilogue block
  for (int blk = 0; blk < 31; ++blk) {
#pragma unroll
    for (int u = 0; u < 16; ++u) {
      step(em[u]);
      em[u] = Fp[u * 32];  // prefetch next block's step u
    }
    Fp += 16 * 32;
  }
#pragma unroll
  for (int u = 0; u < 16; ++u) step(em[u]);

  // terminate: logsumexp over tags of (alpha + trans[STOP, i])
  float pe = EXP2(s + tstop);  // -inf tags -> 0
#pragma unroll
  for (int m = 16; m >= 1; m >>= 1) pe += __shfl_xor(pe, m, 64);
  if (tid == 0) out[b] = (LOG2(pe) + zacc) * LN2;
}

extern "C" void kernel_launch(void* const* d_in, const int* in_sizes, int n_in,
                              void* d_out, int out_size, void* d_ws,
                              size_t ws_size, hipStream_t stream) {
  const float* feat = (const float*)d_in[0];
  const float* trans = (const float*)d_in[1];
  float* out = (float*)d_out;
  const int B = in_sizes[0] / (SEQ * NTAGS);
  crf_fwd_kernel<<<B, 64, 0, stream>>>(feat, trans, out);
}